// Round 4
// baseline (136.181 us; speedup 1.0000x reference)
//
#include <hip/hip_runtime.h>
#include <hip/hip_bf16.h>
#include <stdint.h>

// Problem constants
#define NB 16
#define NS 4096
#define NF 256
#define NH 64
#define NEXP 16

typedef __attribute__((ext_vector_type(8))) short     bf16x8;
typedef __attribute__((ext_vector_type(4))) float     f32x4;
typedef __attribute__((ext_vector_type(2))) unsigned  u32x2;
typedef __attribute__((ext_vector_type(8))) unsigned short u16x8;

// workspace layout (bytes)
#define PART_OFF   0u          // [32][16][256] f32 partial colsums
#define GATE_OFF   524288u     // [16][16] f32 gates
#define BIASC_OFF  525312u     // [16][256] f32 combined bias
#define W1T_OFF    541696u     // [16] x 32768B : [kc8][hd64][64B]
#define W2T_OFF    1065984u    // [16] x 32768B : [hc8][f256][16B]

__device__ __forceinline__ unsigned short bfr(float f) {
  unsigned u = __float_as_uint(f);
  u += 0x7fffu + ((u >> 16) & 1u);
  return (unsigned short)(u >> 16);
}
__device__ __forceinline__ unsigned pk(float a, float b) {
  __hip_bfloat162 t = __float22bfloat162_rn(make_float2(a, b));
  union { __hip_bfloat162 h; unsigned u; } cv; cv.h = t; return cv.u;
}
__device__ __forceinline__ void stage16(const void* g, void* l) {
  __builtin_amdgcn_global_load_lds((const __attribute__((address_space(1))) void*)g,
                                   (__attribute__((address_space(3))) void*)l, 16, 0, 0);
}

// ---------------- kernel 1: colsum (blk<512) + weight prep (blk>=512) --------
__global__ void k_pre(const float* __restrict__ x, const float* __restrict__ W1,
                      const float* __restrict__ W2, uint8_t* __restrict__ wsb) {
  const int blk = blockIdx.x;
  if (blk < 512) {
    const int b  = blk >> 5;
    const int ch = blk & 31;
    const int f  = threadIdx.x;
    const float* xp = x + ((size_t)b * NS + (size_t)ch * 128) * NF + f;
    float s = 0.0f;
    for (int i = 0; i < 128; ++i) s += xp[(size_t)i * NF];
    ((float*)(wsb + PART_OFF))[(size_t)(ch * 16 + b) * NF + f] = s;
    return;
  }
  const int u = (blk - 512) * 256 + threadIdx.x;   // 0..65535 units of 16B
  u16x8 vals;
  if (u < 32768) {
    // W1T unit: u = e*2048 + hd*32 + kc   (k = kc*8 + j)
    const int e  = u >> 11;
    const int r  = u & 2047;
    const int hd = r >> 5;
    const int kc = r & 31;
    const float* src = W1 + (size_t)e * (NF * NH) + (size_t)(kc * 8) * NH + hd;
#pragma unroll
    for (int j = 0; j < 8; ++j) vals[j] = bfr(src[(size_t)j * NH]);
    const int dst = (kc >> 2) * 4096 + hd * 64 + (kc & 3) * 16;
    *(u16x8*)(wsb + W1T_OFF + (size_t)e * 32768 + dst) = vals;
  } else {
    // W2T unit: u2 = e*2048 + f*8 + hc    (hd = hc*8 + j)
    const int u2 = u - 32768;
    const int e  = u2 >> 11;
    const int r  = u2 & 2047;
    const int f  = r >> 3;
    const int hc = r & 7;
    const float* src = W2 + (size_t)e * (NH * NF) + (size_t)(hc * 8) * NF + f;
#pragma unroll
    for (int j = 0; j < 8; ++j) vals[j] = bfr(src[(size_t)j * NF]);
    const int dst = hc * 4096 + f * 16;
    *(u16x8*)(wsb + W2T_OFF + (size_t)e * 32768 + dst) = vals;
  }
}

// ---------------- kernel 2: gates + combined bias ----------------------------
__global__ void k_gate(const float* __restrict__ Wg, const float* __restrict__ bg,
                       const float* __restrict__ b2, uint8_t* __restrict__ wsb) {
  __shared__ float cs[16][256];
  __shared__ float lg[16][16];
  __shared__ float gs[16][16];
  const float* part  = (const float*)(wsb + PART_OFF);
  float* gate  = (float*)(wsb + GATE_OFF);
  float* biasc = (float*)(wsb + BIASC_OFF);
  const int t = threadIdx.x;
  for (int b = 0; b < 16; ++b) {
    float s = 0.0f;
    for (int ch = 0; ch < 32; ++ch) s += part[(size_t)(ch * 16 + b) * NF + t];
    cs[b][t] = s * (1.0f / 4096.0f);
  }
  __syncthreads();
  {
    const int b = t >> 4, e = t & 15;
    float acc = bg[e];
    for (int f = 0; f < NF; ++f) acc += cs[b][f] * Wg[f * 16 + e];
    lg[b][e] = acc;
  }
  __syncthreads();
  {
    const int b = t >> 4, e = t & 15;
    float m = lg[b][0];
    for (int j = 1; j < 16; ++j) m = fmaxf(m, lg[b][j]);
    float den = 0.0f;
    for (int j = 0; j < 16; ++j) den += __expf(lg[b][j] - m);
    float g = __expf(lg[b][e] - m) / den;
    gate[b * 16 + e] = g;
    gs[b][e] = g;
  }
  __syncthreads();
  for (int b = 0; b < 16; ++b) {
    float acc = 0.0f;
    for (int e = 0; e < 16; ++e) acc += gs[b][e] * b2[e * NF + t];
    biasc[b * NF + t] = acc;
  }
}

// ---------------- kernel 3: fused all-expert FFN ------------------------------
// 512 blocks x 512 thr (8 waves); block = 128 tokens of one batch.
// LDS 96KB: W1 dbuf [0,64K), hT dbuf [64K,96K). W2 fragments live in registers
// (loaded one expert ahead from global). One raw barrier per expert with
// counted vmcnt(8): this iter's 8 w2r loads stay in flight; the 4 W1 stages
// (oldest outstanding VMEM) must land before the next iter reads them.
__global__ __launch_bounds__(512, 2)
void k_main(const float* __restrict__ x, const float* __restrict__ b1g,
            const uint8_t* __restrict__ wsb, float* __restrict__ out) {
  __shared__ __align__(16) uint8_t lds[98304];

  const int tid  = threadIdx.x;
  const int w    = tid >> 6;
  const int lane = tid & 63;
  const int c    = lane & 15;
  const int q    = lane >> 4;
  const int wh   = w & 1;          // G1: hd half (32 rows)
  const int wt   = w >> 1;         // G1: token quarter (32)
  const int wf2  = w >> 1;         // G2: f slice (64)
  const int wt2  = w & 1;          // G2: token half (64)
  const int blk  = blockIdx.x;
  const int b    = blk >> 5;

  const float* gate_ws = (const float*)(wsb + GATE_OFF) + b * 16;
  const float* biasc   = (const float*)(wsb + BIASC_OFF) + b * NF;
  const uint8_t* w1src = wsb + W1T_OFF;
  const uint8_t* w2src = wsb + W2T_OFF;

  // per-thread W2 fragment offsets: frag(ks2,m2) at (ks2*4+q)*4096 + (wf2*64+m2*16+c)*16
  const int w2fo = q * 4096 + (wf2 * 64 + c) * 16;

  // ---- prologue: stage W1(0) into parity 0 ----
#pragma unroll
  for (int i = 0; i < 4; ++i)
    stage16(w1src + i * 8192 + tid * 16, lds + i * 8192 + tid * 16);

  // ---- X preload -> bf16 B-fragments (overlaps staging latency) ----
  bf16x8 xf[2][8];
  {
    const int row0 = blk * 128 + wt * 32;
#pragma unroll
    for (int n = 0; n < 2; ++n) {
      const float* xp = x + (size_t)(row0 + n * 16 + c) * NF + q * 8;
#pragma unroll
      for (int ks = 0; ks < 8; ++ks) {
        f32x4 v0 = *(const f32x4*)(xp + ks * 32);
        f32x4 v1 = *(const f32x4*)(xp + ks * 32 + 4);
        union { unsigned u[4]; bf16x8 v; } cv;
        cv.u[0] = pk(v0[0], v0[1]); cv.u[1] = pk(v0[2], v0[3]);
        cv.u[2] = pk(v1[0], v1[1]); cv.u[3] = pk(v1[2], v1[3]);
        xf[n][ks] = cv.v;
      }
    }
  }

  const f32x4 fzero = {0.0f, 0.0f, 0.0f, 0.0f};
  f32x4 acc2[4][4];
#pragma unroll
  for (int i = 0; i < 4; ++i)
#pragma unroll
    for (int j = 0; j < 4; ++j) acc2[i][j] = fzero;

  bf16x8 w2r[2][4];   // W2(e) fragments, loaded in iter e, used by GEMM2(e) in iter e+1

  __syncthreads();   // full drain once: W1(0) staged, X loaded

  const float K1 = -2.3021858962f;      // -2*sqrt(2/pi)*log2(e)
  const float KA = -0.102942243f;       // K1*0.044715

#pragma unroll 1
  for (int e = 0; e < NEXP; ++e) {
    const int p  = e & 1;
    const int pn = p ^ 1;

    // ---- A: issue stage W1(e+1) -> parity pn (4 global_load_lds, oldest VMEM) ----
    if (e < 15) {
      const uint8_t* src = w1src + (size_t)(e + 1) * 32768;
      uint8_t* dst = lds + pn * 32768;
#pragma unroll
      for (int i = 0; i < 4; ++i)
        stage16(src + i * 8192 + tid * 16, dst + i * 8192 + tid * 16);
    }
    // pin: no VMEM op may cross (keeps stages oldest in vmcnt order)
    __builtin_amdgcn_sched_barrier(0x38F);

    // ---- C: preload hT fragments for GEMM2(e-1) ----
    bf16x8 bb2[2][4];
    if (e > 0) {
      const uint8_t* htp2 = lds + 65536 + pn * 16384;
#pragma unroll
      for (int ks2 = 0; ks2 < 2; ++ks2)
#pragma unroll
        for (int n2 = 0; n2 < 4; ++n2)
          bb2[ks2][n2] = *(const bf16x8*)(htp2 + (ks2 * 4 + q) * 2048 + (wt2 * 64 + n2 * 16 + c) * 16);
    }

    // ---- E: MFMA cluster: GEMM1(e) + GEMM2(e-1) ----
    const uint8_t* w1p = lds + p * 32768;
    f32x4 acc1[2][2];
    acc1[0][0] = fzero; acc1[0][1] = fzero; acc1[1][0] = fzero; acc1[1][1] = fzero;
    __builtin_amdgcn_s_setprio(1);
#pragma unroll
    for (int ks = 0; ks < 8; ++ks) {
      bf16x8 a0 = *(const bf16x8*)(w1p + ks * 4096 + (wh * 32 + c) * 64 + q * 16);
      bf16x8 a1 = *(const bf16x8*)(w1p + ks * 4096 + (wh * 32 + 16 + c) * 64 + q * 16);
      acc1[0][0] = __builtin_amdgcn_mfma_f32_16x16x32_bf16(a0, xf[0][ks], acc1[0][0], 0, 0, 0);
      acc1[0][1] = __builtin_amdgcn_mfma_f32_16x16x32_bf16(a0, xf[1][ks], acc1[0][1], 0, 0, 0);
      acc1[1][0] = __builtin_amdgcn_mfma_f32_16x16x32_bf16(a1, xf[0][ks], acc1[1][0], 0, 0, 0);
      acc1[1][1] = __builtin_amdgcn_mfma_f32_16x16x32_bf16(a1, xf[1][ks], acc1[1][1], 0, 0, 0);
    }
    if (e > 0) {
#pragma unroll
      for (int ks2 = 0; ks2 < 2; ++ks2)
#pragma unroll
        for (int m2 = 0; m2 < 4; ++m2)
#pragma unroll
          for (int n2 = 0; n2 < 4; ++n2)
            acc2[m2][n2] = __builtin_amdgcn_mfma_f32_16x16x32_bf16(w2r[ks2][m2], bb2[ks2][n2], acc2[m2][n2], 0, 0, 0);
    }
    __builtin_amdgcn_s_setprio(0);

    // ---- F: load W2(e) fragments into registers (8 global_load_dwordx4) ----
    {
      const uint8_t* src = w2src + (size_t)e * 32768 + w2fo;
#pragma unroll
      for (int ks2 = 0; ks2 < 2; ++ks2)
#pragma unroll
        for (int m2 = 0; m2 < 4; ++m2)
          w2r[ks2][m2] = *(const bf16x8*)(src + ks2 * 16384 + m2 * 256);
    }

    // ---- G: epilogue(e): bias + gelu*gate -> bf16 -> hT[p] ----
    {
      const float gv = gate_ws[e];
      uint8_t* htp = lds + 65536 + p * 16384;
      f32x4 b1v[2];
#pragma unroll
      for (int m = 0; m < 2; ++m)
        b1v[m] = *(const f32x4*)(b1g + e * NH + wh * 32 + m * 16 + q * 4);
#pragma unroll
      for (int m = 0; m < 2; ++m) {
#pragma unroll
        for (int n = 0; n < 2; ++n) {
          f32x4 hv = acc1[m][n] + b1v[m];
          float o[4];
#pragma unroll
          for (int r = 0; r < 4; ++r) {
            float xx = hv[r];
            float x2 = xx * xx;
            float tt = fmaf(KA, x2, K1);
            float ez = __builtin_amdgcn_exp2f(xx * tt);
            float rc = __builtin_amdgcn_rcpf(ez + 1.0f);
            o[r] = (gv * xx) * rc;
          }
          u32x2 hw;
          hw.x = pk(o[0], o[1]);
          hw.y = pk(o[2], o[3]);
          const int chunk = wh * 4 + m * 2 + (q >> 1);
          const int tok   = wt * 32 + n * 16 + c;
          *(u32x2*)(htp + chunk * 2048 + tok * 16 + (q & 1) * 8) = hw;
        }
      }
    }

    // ---- H+I: counted drain + barrier ----
    // outstanding VMEM: 4 W1 stages (oldest) + 8 w2r loads (newest).
    // vmcnt(8): stages complete; w2r stays in flight (consumed next iter,
    // compiler inserts its own wait before first use). lgkmcnt(0): hT writes visible.
    asm volatile("s_waitcnt vmcnt(8) lgkmcnt(0)" ::: "memory");
    __builtin_amdgcn_s_barrier();
    __builtin_amdgcn_sched_barrier(0);
  }

  // ---- tail: GEMM2(15), hT parity 1, w2r = W2(15) ----
  {
    const uint8_t* htp2 = lds + 65536 + 16384;
#pragma unroll
    for (int ks2 = 0; ks2 < 2; ++ks2) {
      bf16x8 bb2[4];
#pragma unroll
      for (int n2 = 0; n2 < 4; ++n2)
        bb2[n2] = *(const bf16x8*)(htp2 + (ks2 * 4 + q) * 2048 + (wt2 * 64 + n2 * 16 + c) * 16);
#pragma unroll
      for (int m2 = 0; m2 < 4; ++m2)
#pragma unroll
        for (int n2 = 0; n2 < 4; ++n2)
          acc2[m2][n2] = __builtin_amdgcn_mfma_f32_16x16x32_bf16(w2r[ks2][m2], bb2[n2], acc2[m2][n2], 0, 0, 0);
    }
  }

  // ---- output: acc2 + biasc ----
#pragma unroll
  for (int m2 = 0; m2 < 4; ++m2) {
    const int fbase = wf2 * 64 + m2 * 16 + q * 4;
    f32x4 bc = *(const f32x4*)(biasc + fbase);
#pragma unroll
    for (int n2 = 0; n2 < 4; ++n2) {
      const int token = blk * 128 + wt2 * 64 + n2 * 16 + c;
      f32x4 o = acc2[m2][n2] + bc;
      *(f32x4*)(out + (size_t)token * NF + fbase) = o;
    }
  }
}

// ---------------- host launch -------------------------------------------------
extern "C" void kernel_launch(void* const* d_in, const int* in_sizes, int n_in,
                              void* d_out, int out_size, void* d_ws, size_t ws_size,
                              hipStream_t stream) {
  const float* x  = (const float*)d_in[0];
  const float* W1 = (const float*)d_in[1];
  const float* b1 = (const float*)d_in[2];
  const float* W2 = (const float*)d_in[3];
  const float* b2 = (const float*)d_in[4];
  const float* Wg = (const float*)d_in[5];
  const float* bg = (const float*)d_in[6];
  float* out = (float*)d_out;
  uint8_t* wsb = (uint8_t*)d_ws;

  k_pre<<<768, 256, 0, stream>>>(x, W1, W2, wsb);
  k_gate<<<1, 256, 0, stream>>>(Wg, bg, b2, wsb);
  k_main<<<512, 512, 0, stream>>>(x, b1, wsb, out);
}

// Round 5
// 126.652 us; speedup vs baseline: 1.0752x; 1.0752x over previous
//
#include <hip/hip_runtime.h>
#include <hip/hip_bf16.h>
#include <stdint.h>

// Problem constants
#define NB 16
#define NS 4096
#define NF 256
#define NH 64
#define NEXP 16

typedef __attribute__((ext_vector_type(8))) short     bf16x8;
typedef __attribute__((ext_vector_type(4))) float     f32x4;
typedef __attribute__((ext_vector_type(2))) unsigned  u32x2;
typedef __attribute__((ext_vector_type(8))) unsigned short u16x8;

// workspace layout (bytes)
#define PART_OFF   0u          // [32][16][256] f32 partial colsums
#define GATE_OFF   524288u     // [16][16] f32 gates
#define BIASC_OFF  525312u     // [16][256] f32 combined bias
#define W1T_OFF    541696u     // [16] x 32768B : [kc8][hd64][64B]
#define W2T_OFF    1065984u    // [16] x 32768B : [hc8][f256][16B]

__device__ __forceinline__ unsigned short bfr(float f) {
  unsigned u = __float_as_uint(f);
  u += 0x7fffu + ((u >> 16) & 1u);
  return (unsigned short)(u >> 16);
}
__device__ __forceinline__ unsigned pk(float a, float b) {
  __hip_bfloat162 t = __float22bfloat162_rn(make_float2(a, b));
  union { __hip_bfloat162 h; unsigned u; } cv; cv.h = t; return cv.u;
}
__device__ __forceinline__ bf16x8 as_bf(f32x4 v) {
  union { f32x4 f; bf16x8 h; } u; u.f = v; return u.h;
}
__device__ __forceinline__ void stage16(const void* g, void* l) {
  __builtin_amdgcn_global_load_lds((const __attribute__((address_space(1))) void*)g,
                                   (__attribute__((address_space(3))) void*)l, 16, 0, 0);
}

// ---------------- kernel 1: colsum (blk<512) + weight prep (blk>=512) --------
__global__ void k_pre(const float* __restrict__ x, const float* __restrict__ W1,
                      const float* __restrict__ W2, uint8_t* __restrict__ wsb) {
  const int blk = blockIdx.x;
  if (blk < 512) {
    const int b  = blk >> 5;
    const int ch = blk & 31;
    const int f  = threadIdx.x;
    const float* xp = x + ((size_t)b * NS + (size_t)ch * 128) * NF + f;
    float s = 0.0f;
    for (int i = 0; i < 128; ++i) s += xp[(size_t)i * NF];
    ((float*)(wsb + PART_OFF))[(size_t)(ch * 16 + b) * NF + f] = s;
    return;
  }
  const int u = (blk - 512) * 256 + threadIdx.x;   // 0..65535 units of 16B
  u16x8 vals;
  if (u < 32768) {
    // W1T unit: u = e*2048 + hd*32 + kc   (k = kc*8 + j)
    const int e  = u >> 11;
    const int r  = u & 2047;
    const int hd = r >> 5;
    const int kc = r & 31;
    const float* src = W1 + (size_t)e * (NF * NH) + (size_t)(kc * 8) * NH + hd;
#pragma unroll
    for (int j = 0; j < 8; ++j) vals[j] = bfr(src[(size_t)j * NH]);
    const int dst = (kc >> 2) * 4096 + hd * 64 + (kc & 3) * 16;
    *(u16x8*)(wsb + W1T_OFF + (size_t)e * 32768 + dst) = vals;
  } else {
    // W2T unit: u2 = e*2048 + f*8 + hc    (hd = hc*8 + j)
    const int u2 = u - 32768;
    const int e  = u2 >> 11;
    const int r  = u2 & 2047;
    const int f  = r >> 3;
    const int hc = r & 7;
    const float* src = W2 + (size_t)e * (NH * NF) + (size_t)(hc * 8) * NF + f;
#pragma unroll
    for (int j = 0; j < 8; ++j) vals[j] = bfr(src[(size_t)j * NF]);
    const int dst = hc * 4096 + f * 16;
    *(u16x8*)(wsb + W2T_OFF + (size_t)e * 32768 + dst) = vals;
  }
}

// ---------------- kernel 2: gates + combined bias ----------------------------
__global__ void k_gate(const float* __restrict__ Wg, const float* __restrict__ bg,
                       const float* __restrict__ b2, uint8_t* __restrict__ wsb) {
  __shared__ float cs[16][256];
  __shared__ float lg[16][16];
  __shared__ float gs[16][16];
  const float* part  = (const float*)(wsb + PART_OFF);
  float* gate  = (float*)(wsb + GATE_OFF);
  float* biasc = (float*)(wsb + BIASC_OFF);
  const int t = threadIdx.x;
  for (int b = 0; b < 16; ++b) {
    float s = 0.0f;
    for (int ch = 0; ch < 32; ++ch) s += part[(size_t)(ch * 16 + b) * NF + t];
    cs[b][t] = s * (1.0f / 4096.0f);
  }
  __syncthreads();
  {
    const int b = t >> 4, e = t & 15;
    float acc = bg[e];
    for (int f = 0; f < NF; ++f) acc += cs[b][f] * Wg[f * 16 + e];
    lg[b][e] = acc;
  }
  __syncthreads();
  {
    const int b = t >> 4, e = t & 15;
    float m = lg[b][0];
    for (int j = 1; j < 16; ++j) m = fmaxf(m, lg[b][j]);
    float den = 0.0f;
    for (int j = 0; j < 16; ++j) den += __expf(lg[b][j] - m);
    float g = __expf(lg[b][e] - m) / den;
    gate[b * 16 + e] = g;
    gs[b][e] = g;
  }
  __syncthreads();
  for (int b = 0; b < 16; ++b) {
    float acc = 0.0f;
    for (int e = 0; e < 16; ++e) acc += gs[b][e] * b2[e * NF + t];
    biasc[b * NF + t] = acc;
  }
}

// ---------------- kernel 3: fused all-expert FFN, role-split waves -----------
// 512 blocks x 512 thr; block = 128 tokens of one batch.
// Waves 0-3 (G1): per wave 32 tokens x all 64 hd: GEMM1 + gelu epilogue -> hT.
// Waves 4-7 (G2): per wave 64 f x all 128 tokens: GEMM2 from hT + reg-held W2.
// Per SIMD: one G1-wave + one G2-wave -> MFMA/VALU/DS pipes overlap across roles.
// LDS 96KB: W1 dbuf [0,64K), hT dbuf [64K,96K). One __syncthreads per expert.
// Register pool R[32] (static idx): G1 uses R[0..7]=acc1, R[8..23]=xf(bf16);
// G2 uses R[0..31]=acc2. Shared so both roles fit one allocation (~220 VGPR).
__global__ __launch_bounds__(512, 2)
void k_main(const float* __restrict__ x, const float* __restrict__ b1g,
            const uint8_t* __restrict__ wsb, float* __restrict__ out) {
  __shared__ __align__(16) uint8_t lds[98304];

  const int tid  = threadIdx.x;
  const int w    = tid >> 6;
  const int lane = tid & 63;
  const int c    = lane & 15;
  const int q    = lane >> 4;
  const int r4   = w & 3;          // G1: token quarter; G2: f quarter
  const bool g1  = (w < 4);
  const int blk  = blockIdx.x;
  const int b    = blk >> 5;

  const float* gate_ws = (const float*)(wsb + GATE_OFF) + b * 16;
  const float* biasc   = (const float*)(wsb + BIASC_OFF) + b * NF;
  const uint8_t* w1src = wsb + W1T_OFF;
  const uint8_t* w2src = wsb + W2T_OFF;

  const f32x4 fz = {0.0f, 0.0f, 0.0f, 0.0f};
  f32x4 R[32];

  // ---- prologue: stage W1(0) into parity 0 ----
#pragma unroll
  for (int i = 0; i < 4; ++i)
    stage16(w1src + i * 8192 + tid * 16, lds + i * 8192 + tid * 16);

  if (g1) {
    // X preload -> bf16 B-fragments in R[8..23] (overlaps staging latency)
    const int row0 = blk * 128 + r4 * 32;
#pragma unroll
    for (int n = 0; n < 2; ++n) {
      const float* xp = x + (size_t)(row0 + n * 16 + c) * NF + q * 8;
#pragma unroll
      for (int ks = 0; ks < 8; ++ks) {
        f32x4 v0 = *(const f32x4*)(xp + ks * 32);
        f32x4 v1 = *(const f32x4*)(xp + ks * 32 + 4);
        union { unsigned u[4]; f32x4 f; } cv;
        cv.u[0] = pk(v0[0], v0[1]); cv.u[1] = pk(v0[2], v0[3]);
        cv.u[2] = pk(v1[0], v1[1]); cv.u[3] = pk(v1[2], v1[3]);
        R[8 + n * 8 + ks] = cv.f;
      }
    }
  } else {
#pragma unroll
    for (int i = 0; i < 32; ++i) R[i] = fz;   // acc2
  }

  bf16x8 w2r[2][4];   // W2(e) A-frags, loaded in iter e, used in iter e+1 (G2 only)

  __syncthreads();   // W1(0) staged

  const float K1 = -2.3021858962f;      // -2*sqrt(2/pi)*log2(e)
  const float KA = -0.102942243f;       // K1*0.044715

#pragma unroll 1
  for (int e = 0; e < NEXP; ++e) {
    const int p  = e & 1;
    const int pn = p ^ 1;

    // ---- stage W1(e+1) -> parity pn (all waves share the staging) ----
    if (e < 15) {
      const uint8_t* src = w1src + (size_t)(e + 1) * 32768;
      uint8_t* dst = lds + pn * 32768;
#pragma unroll
      for (int i = 0; i < 4; ++i)
        stage16(src + i * 8192 + tid * 16, dst + i * 8192 + tid * 16);
    }

    if (g1) {
      // ---- GEMM1(e): D[hd 64][tok 32] = W1T x X^T ----
      const uint8_t* w1p = lds + p * 32768;
#pragma unroll
      for (int i = 0; i < 8; ++i) R[i] = fz;   // acc1
      __builtin_amdgcn_s_setprio(1);
#pragma unroll
      for (int ks = 0; ks < 8; ++ks) {
        bf16x8 am[4];
#pragma unroll
        for (int m = 0; m < 4; ++m)
          am[m] = *(const bf16x8*)(w1p + ks * 4096 + (m * 16 + c) * 64 + q * 16);
#pragma unroll
        for (int m = 0; m < 4; ++m) {
          R[m * 2 + 0] = __builtin_amdgcn_mfma_f32_16x16x32_bf16(am[m], as_bf(R[8 + ks]),     R[m * 2 + 0], 0, 0, 0);
          R[m * 2 + 1] = __builtin_amdgcn_mfma_f32_16x16x32_bf16(am[m], as_bf(R[16 + ks]),    R[m * 2 + 1], 0, 0, 0);
        }
      }
      __builtin_amdgcn_s_setprio(0);

      // ---- epilogue(e): bias + gelu*gate -> bf16 -> hT[p] ----
      const float gv = gate_ws[e];
      uint8_t* htp = lds + 65536 + p * 16384;
#pragma unroll
      for (int m = 0; m < 4; ++m) {
        f32x4 b1v = *(const f32x4*)(b1g + e * NH + m * 16 + q * 4);
#pragma unroll
        for (int n = 0; n < 2; ++n) {
          f32x4 hv = R[m * 2 + n] + b1v;
          float o[4];
#pragma unroll
          for (int r = 0; r < 4; ++r) {
            float xx = hv[r];
            float x2 = xx * xx;
            float tt = fmaf(KA, x2, K1);
            float ez = __builtin_amdgcn_exp2f(xx * tt);
            float rc = __builtin_amdgcn_rcpf(ez + 1.0f);
            o[r] = (gv * xx) * rc;
          }
          u32x2 hw;
          hw.x = pk(o[0], o[1]);
          hw.y = pk(o[2], o[3]);
          const int chunk = m * 2 + (q >> 1);
          const int tok   = r4 * 32 + n * 16 + c;
          *(u32x2*)(htp + chunk * 2048 + tok * 16 + (q & 1) * 8) = hw;
        }
      }
    } else {
      // ---- GEMM2(e-1): D[f 64][tok 128] += W2T x hT, reads hT[pn], w2r ----
      if (e > 0) {
        const uint8_t* htp2 = lds + 65536 + pn * 16384;
        __builtin_amdgcn_s_setprio(1);
#pragma unroll
        for (int ks2 = 0; ks2 < 2; ++ks2) {
          bf16x8 bb2[8];
#pragma unroll
          for (int n2 = 0; n2 < 8; ++n2)
            bb2[n2] = *(const bf16x8*)(htp2 + (ks2 * 4 + q) * 2048 + (n2 * 16 + c) * 16);
#pragma unroll
          for (int m2 = 0; m2 < 4; ++m2)
#pragma unroll
            for (int n2 = 0; n2 < 8; ++n2)
              R[m2 * 8 + n2] = __builtin_amdgcn_mfma_f32_16x16x32_bf16(w2r[ks2][m2], bb2[n2], R[m2 * 8 + n2], 0, 0, 0);
        }
        __builtin_amdgcn_s_setprio(0);
      }
      // ---- load W2(e) fragments (used next iter; drained by __syncthreads) ----
      const uint8_t* src = w2src + (size_t)e * 32768 + q * 4096 + (r4 * 64 + c) * 16;
#pragma unroll
      for (int ks2 = 0; ks2 < 2; ++ks2)
#pragma unroll
        for (int m2 = 0; m2 < 4; ++m2)
          w2r[ks2][m2] = *(const bf16x8*)(src + ks2 * 16384 + m2 * 256);
    }

    __syncthreads();
  }

  // ---- tail (G2 only): GEMM2(15) from hT parity 1, then store ----
  if (!g1) {
    const uint8_t* htp2 = lds + 65536 + 16384;
#pragma unroll
    for (int ks2 = 0; ks2 < 2; ++ks2) {
      bf16x8 bb2[8];
#pragma unroll
      for (int n2 = 0; n2 < 8; ++n2)
        bb2[n2] = *(const bf16x8*)(htp2 + (ks2 * 4 + q) * 2048 + (n2 * 16 + c) * 16);
#pragma unroll
      for (int m2 = 0; m2 < 4; ++m2)
#pragma unroll
        for (int n2 = 0; n2 < 8; ++n2)
          R[m2 * 8 + n2] = __builtin_amdgcn_mfma_f32_16x16x32_bf16(w2r[ks2][m2], bb2[n2], R[m2 * 8 + n2], 0, 0, 0);
    }
#pragma unroll
    for (int m2 = 0; m2 < 4; ++m2) {
      const int fbase = r4 * 64 + m2 * 16 + q * 4;
      f32x4 bc = *(const f32x4*)(biasc + fbase);
#pragma unroll
      for (int n2 = 0; n2 < 8; ++n2) {
        const int token = blk * 128 + n2 * 16 + c;
        f32x4 o = R[m2 * 8 + n2] + bc;
        *(f32x4*)(out + (size_t)token * NF + fbase) = o;
      }
    }
  }
}

// ---------------- host launch -------------------------------------------------
extern "C" void kernel_launch(void* const* d_in, const int* in_sizes, int n_in,
                              void* d_out, int out_size, void* d_ws, size_t ws_size,
                              hipStream_t stream) {
  const float* x  = (const float*)d_in[0];
  const float* W1 = (const float*)d_in[1];
  const float* b1 = (const float*)d_in[2];
  const float* W2 = (const float*)d_in[3];
  const float* b2 = (const float*)d_in[4];
  const float* Wg = (const float*)d_in[5];
  const float* bg = (const float*)d_in[6];
  float* out = (float*)d_out;
  uint8_t* wsb = (uint8_t*)d_ws;

  k_pre<<<768, 256, 0, stream>>>(x, W1, W2, wsb);
  k_gate<<<1, 256, 0, stream>>>(Wg, bg, b2, wsb);
  k_main<<<512, 512, 0, stream>>>(x, b1, wsb, out);
}

// Round 6
// 124.116 us; speedup vs baseline: 1.0972x; 1.0204x over previous
//
#include <hip/hip_runtime.h>
#include <hip/hip_bf16.h>
#include <stdint.h>

// Problem constants
#define NB 16
#define NS 4096
#define NF 256
#define NH 64
#define NEXP 16

typedef __attribute__((ext_vector_type(8))) short     bf16x8;
typedef __attribute__((ext_vector_type(4))) float     f32x4;
typedef __attribute__((ext_vector_type(2))) unsigned  u32x2;
typedef __attribute__((ext_vector_type(8))) unsigned short u16x8;

// workspace layout (bytes)
#define PART_OFF   0u          // [32][16][256] f32 partial colsums
#define GATE_OFF   524288u     // [16][16] f32 gates
#define BIASC_OFF  525312u     // [16][256] f32 combined bias
#define W1T_OFF    541696u     // [16] x 32768B : [kc8][hd64][64B]
#define W2T_OFF    1065984u    // [16] x 32768B : [hc8][f256][16B]

__device__ __forceinline__ unsigned short bfr(float f) {
  unsigned u = __float_as_uint(f);
  u += 0x7fffu + ((u >> 16) & 1u);
  return (unsigned short)(u >> 16);
}
__device__ __forceinline__ unsigned pk(float a, float b) {
  __hip_bfloat162 t = __float22bfloat162_rn(make_float2(a, b));
  union { __hip_bfloat162 h; unsigned u; } cv; cv.h = t; return cv.u;
}
__device__ __forceinline__ bf16x8 as_bf(f32x4 v) {
  union { f32x4 f; bf16x8 h; } u; u.f = v; return u.h;
}
__device__ __forceinline__ void stage16(const void* g, void* l) {
  __builtin_amdgcn_global_load_lds((const __attribute__((address_space(1))) void*)g,
                                   (__attribute__((address_space(3))) void*)l, 16, 0, 0);
}

// ---------------- kernel 1: colsum (blk<512) + weight prep (blk>=512) --------
__global__ void k_pre(const float* __restrict__ x, const float* __restrict__ W1,
                      const float* __restrict__ W2, uint8_t* __restrict__ wsb) {
  const int blk = blockIdx.x;
  if (blk < 512) {
    const int b  = blk >> 5;
    const int ch = blk & 31;
    const int f  = threadIdx.x;
    const float* xp = x + ((size_t)b * NS + (size_t)ch * 128) * NF + f;
    float s = 0.0f;
    for (int i = 0; i < 128; ++i) s += xp[(size_t)i * NF];
    ((float*)(wsb + PART_OFF))[(size_t)(ch * 16 + b) * NF + f] = s;
    return;
  }
  const int u = (blk - 512) * 256 + threadIdx.x;   // 0..65535 units of 16B
  u16x8 vals;
  if (u < 32768) {
    // W1T unit: u = e*2048 + hd*32 + kc   (k = kc*8 + j)
    const int e  = u >> 11;
    const int r  = u & 2047;
    const int hd = r >> 5;
    const int kc = r & 31;
    const float* src = W1 + (size_t)e * (NF * NH) + (size_t)(kc * 8) * NH + hd;
#pragma unroll
    for (int j = 0; j < 8; ++j) vals[j] = bfr(src[(size_t)j * NH]);
    const int dst = (kc >> 2) * 4096 + hd * 64 + (kc & 3) * 16;
    *(u16x8*)(wsb + W1T_OFF + (size_t)e * 32768 + dst) = vals;
  } else {
    // W2T unit: u2 = e*2048 + f*8 + hc    (hd = hc*8 + j)
    const int u2 = u - 32768;
    const int e  = u2 >> 11;
    const int r  = u2 & 2047;
    const int f  = r >> 3;
    const int hc = r & 7;
    const float* src = W2 + (size_t)e * (NH * NF) + (size_t)(hc * 8) * NF + f;
#pragma unroll
    for (int j = 0; j < 8; ++j) vals[j] = bfr(src[(size_t)j * NF]);
    const int dst = hc * 4096 + f * 16;
    *(u16x8*)(wsb + W2T_OFF + (size_t)e * 32768 + dst) = vals;
  }
}

// ---------------- kernel 2: gates + combined bias ----------------------------
__global__ void k_gate(const float* __restrict__ Wg, const float* __restrict__ bg,
                       const float* __restrict__ b2, uint8_t* __restrict__ wsb) {
  __shared__ float cs[16][256];
  __shared__ float lg[16][16];
  __shared__ float gs[16][16];
  const float* part  = (const float*)(wsb + PART_OFF);
  float* gate  = (float*)(wsb + GATE_OFF);
  float* biasc = (float*)(wsb + BIASC_OFF);
  const int t = threadIdx.x;
  for (int b = 0; b < 16; ++b) {
    float s = 0.0f;
    for (int ch = 0; ch < 32; ++ch) s += part[(size_t)(ch * 16 + b) * NF + t];
    cs[b][t] = s * (1.0f / 4096.0f);
  }
  __syncthreads();
  {
    const int b = t >> 4, e = t & 15;
    float acc = bg[e];
    for (int f = 0; f < NF; ++f) acc += cs[b][f] * Wg[f * 16 + e];
    lg[b][e] = acc;
  }
  __syncthreads();
  {
    const int b = t >> 4, e = t & 15;
    float m = lg[b][0];
    for (int j = 1; j < 16; ++j) m = fmaxf(m, lg[b][j]);
    float den = 0.0f;
    for (int j = 0; j < 16; ++j) den += __expf(lg[b][j] - m);
    float g = __expf(lg[b][e] - m) / den;
    gate[b * 16 + e] = g;
    gs[b][e] = g;
  }
  __syncthreads();
  for (int b = 0; b < 16; ++b) {
    float acc = 0.0f;
    for (int e = 0; e < 16; ++e) acc += gs[b][e] * b2[e * NF + t];
    biasc[b * NF + t] = acc;
  }
}

// ---------------- kernel 3: fused all-expert FFN, 12-wave role-split ---------
// 512 blocks x 768 thr (12 waves = 3/SIMD); block = 128 tokens of one batch.
// Waves 0-3  (G1): 32 tokens x all 64 hd: GEMM1 + gelu epilogue -> hT.
// Waves 4-11 (G2): 32 f x all 128 tokens: GEMM2 from hT + reg-held W2 (16 VGPR);
//                  G2 threads also issue W1 staging and w2r loads (lighter role).
// Each SIMD hosts 1 G1 + 2 G2 -> MFMA/VALU/DS overlap across roles at 3 waves.
// LDS 96KB: W1 dbuf [0,64K), hT dbuf [64K,96K). One __syncthreads per expert.
// Register pool R[16] f32x4 (64 VGPR): G1 -> xf (bf16 X-frags); G2 -> acc2.
// All waves target <=170 VGPR so 3/SIMD is schedulable (launch_bounds 768,3).
__global__ __launch_bounds__(768, 3)
void k_main(const float* __restrict__ x, const float* __restrict__ b1g,
            const uint8_t* __restrict__ wsb, float* __restrict__ out) {
  __shared__ __align__(16) uint8_t lds[98304];

  const int tid  = threadIdx.x;
  const int w    = tid >> 6;
  const int lane = tid & 63;
  const int c    = lane & 15;
  const int q    = lane >> 4;
  const bool g1  = (w < 4);
  const int fs   = (w - 4) * 32;   // G2: f-slice base (32 f per wave)
  const int st   = tid - 256;      // G2 staging index in [0,512)
  const int blk  = blockIdx.x;
  const int b    = blk >> 5;

  const float* gate_ws = (const float*)(wsb + GATE_OFF) + b * 16;
  const float* biasc   = (const float*)(wsb + BIASC_OFF) + b * NF;
  const uint8_t* w1src = wsb + W1T_OFF;
  const uint8_t* w2src = wsb + W2T_OFF;

  const f32x4 fz = {0.0f, 0.0f, 0.0f, 0.0f};
  f32x4 R[16];        // G1: xf[n*8+ks] (bf16x8 bits); G2: acc2[m2*8+n2]
  bf16x8 w2r[2][2];   // G2: W2(e) A-frags (16 VGPR), loaded iter e, used e+1

  // ---- prologue ----
  if (!g1) {
    // stage W1(0) into parity 0 (512 G2 threads x 4 units)
#pragma unroll
    for (int i = 0; i < 4; ++i)
      stage16(w1src + i * 8192 + st * 16, lds + i * 8192 + st * 16);
#pragma unroll
    for (int i = 0; i < 16; ++i) R[i] = fz;   // acc2
  } else {
    // X preload -> bf16 B-fragments in R[0..15]
    const int row0 = blk * 128 + w * 32;
#pragma unroll
    for (int n = 0; n < 2; ++n) {
      const float* xp = x + (size_t)(row0 + n * 16 + c) * NF + q * 8;
#pragma unroll
      for (int ks = 0; ks < 8; ++ks) {
        f32x4 v0 = *(const f32x4*)(xp + ks * 32);
        f32x4 v1 = *(const f32x4*)(xp + ks * 32 + 4);
        union { unsigned u[4]; f32x4 f; } cv;
        cv.u[0] = pk(v0[0], v0[1]); cv.u[1] = pk(v0[2], v0[3]);
        cv.u[2] = pk(v1[0], v1[1]); cv.u[3] = pk(v1[2], v1[3]);
        R[n * 8 + ks] = cv.f;
      }
    }
  }

  __syncthreads();   // W1(0) staged

  const float K1 = -2.3021858962f;      // -2*sqrt(2/pi)*log2(e)
  const float KA = -0.102942243f;       // K1*0.044715

#pragma unroll 1
  for (int e = 0; e < NEXP; ++e) {
    const int p  = e & 1;
    const int pn = p ^ 1;

    if (g1) {
      // ---- GEMM1(e): D[hd 64][tok 32] = W1T x X^T (reads W1 buf p) ----
      const uint8_t* w1p = lds + p * 32768;
      f32x4 a1[4][2];
#pragma unroll
      for (int m = 0; m < 4; ++m) { a1[m][0] = fz; a1[m][1] = fz; }
      __builtin_amdgcn_s_setprio(1);
#pragma unroll
      for (int ks = 0; ks < 8; ++ks) {
        bf16x8 am[4];
#pragma unroll
        for (int m = 0; m < 4; ++m)
          am[m] = *(const bf16x8*)(w1p + ks * 4096 + (m * 16 + c) * 64 + q * 16);
#pragma unroll
        for (int m = 0; m < 4; ++m) {
          a1[m][0] = __builtin_amdgcn_mfma_f32_16x16x32_bf16(am[m], as_bf(R[ks]),     a1[m][0], 0, 0, 0);
          a1[m][1] = __builtin_amdgcn_mfma_f32_16x16x32_bf16(am[m], as_bf(R[8 + ks]), a1[m][1], 0, 0, 0);
        }
      }
      __builtin_amdgcn_s_setprio(0);

      // ---- epilogue(e): bias + gelu*gate -> bf16 -> hT[p] ----
      const float gv = gate_ws[e];
      uint8_t* htp = lds + 65536 + p * 16384;
#pragma unroll
      for (int m = 0; m < 4; ++m) {
        f32x4 b1v = *(const f32x4*)(b1g + e * NH + m * 16 + q * 4);
#pragma unroll
        for (int n = 0; n < 2; ++n) {
          f32x4 hv = a1[m][n] + b1v;
          float o[4];
#pragma unroll
          for (int r = 0; r < 4; ++r) {
            float xx = hv[r];
            float x2 = xx * xx;
            float tt = fmaf(KA, x2, K1);
            float ez = __builtin_amdgcn_exp2f(xx * tt);
            float rc = __builtin_amdgcn_rcpf(ez + 1.0f);
            o[r] = (gv * xx) * rc;
          }
          u32x2 hw;
          hw.x = pk(o[0], o[1]);
          hw.y = pk(o[2], o[3]);
          const int chunk = m * 2 + (q >> 1);
          const int tok   = w * 32 + n * 16 + c;
          *(u32x2*)(htp + chunk * 2048 + tok * 16 + (q & 1) * 8) = hw;
        }
      }
    } else {
      // ---- stage W1(e+1) -> parity pn (G2 threads only) ----
      if (e < 15) {
        const uint8_t* src = w1src + (size_t)(e + 1) * 32768;
        uint8_t* dst = lds + pn * 32768;
#pragma unroll
        for (int i = 0; i < 4; ++i)
          stage16(src + i * 8192 + st * 16, dst + i * 8192 + st * 16);
      }

      // ---- GEMM2(e-1): D[f 32][tok 128] += W2T x hT (reads hT[pn], w2r) ----
      if (e > 0) {
        const uint8_t* htp2 = lds + 65536 + pn * 16384;
        __builtin_amdgcn_s_setprio(1);
#pragma unroll
        for (int ks2 = 0; ks2 < 2; ++ks2) {
          bf16x8 bb2[8];
#pragma unroll
          for (int n2 = 0; n2 < 8; ++n2)
            bb2[n2] = *(const bf16x8*)(htp2 + (ks2 * 4 + q) * 2048 + (n2 * 16 + c) * 16);
#pragma unroll
          for (int m2 = 0; m2 < 2; ++m2)
#pragma unroll
            for (int n2 = 0; n2 < 8; ++n2)
              R[m2 * 8 + n2] = __builtin_amdgcn_mfma_f32_16x16x32_bf16(w2r[ks2][m2], bb2[n2], R[m2 * 8 + n2], 0, 0, 0);
        }
        __builtin_amdgcn_s_setprio(0);
      }

      // ---- load W2(e) fragments (used next iter; drained by __syncthreads) ----
      const uint8_t* src = w2src + (size_t)e * 32768 + q * 4096 + (fs + c) * 16;
#pragma unroll
      for (int ks2 = 0; ks2 < 2; ++ks2)
#pragma unroll
        for (int m2 = 0; m2 < 2; ++m2)
          w2r[ks2][m2] = *(const bf16x8*)(src + ks2 * 16384 + m2 * 256);
    }

    __syncthreads();
  }

  // ---- tail (G2 only): GEMM2(15) from hT parity 1, then store ----
  if (!g1) {
    const uint8_t* htp2 = lds + 65536 + 16384;
#pragma unroll
    for (int ks2 = 0; ks2 < 2; ++ks2) {
      bf16x8 bb2[8];
#pragma unroll
      for (int n2 = 0; n2 < 8; ++n2)
        bb2[n2] = *(const bf16x8*)(htp2 + (ks2 * 4 + q) * 2048 + (n2 * 16 + c) * 16);
#pragma unroll
      for (int m2 = 0; m2 < 2; ++m2)
#pragma unroll
        for (int n2 = 0; n2 < 8; ++n2)
          R[m2 * 8 + n2] = __builtin_amdgcn_mfma_f32_16x16x32_bf16(w2r[ks2][m2], bb2[n2], R[m2 * 8 + n2], 0, 0, 0);
    }
#pragma unroll
    for (int m2 = 0; m2 < 2; ++m2) {
      const int fbase = fs + m2 * 16 + q * 4;
      f32x4 bc = *(const f32x4*)(biasc + fbase);
#pragma unroll
      for (int n2 = 0; n2 < 8; ++n2) {
        const int token = blk * 128 + n2 * 16 + c;
        f32x4 o = R[m2 * 8 + n2] + bc;
        *(f32x4*)(out + (size_t)token * NF + fbase) = o;
      }
    }
  }
}

// ---------------- host launch -------------------------------------------------
extern "C" void kernel_launch(void* const* d_in, const int* in_sizes, int n_in,
                              void* d_out, int out_size, void* d_ws, size_t ws_size,
                              hipStream_t stream) {
  const float* x  = (const float*)d_in[0];
  const float* W1 = (const float*)d_in[1];
  const float* b1 = (const float*)d_in[2];
  const float* W2 = (const float*)d_in[3];
  const float* b2 = (const float*)d_in[4];
  const float* Wg = (const float*)d_in[5];
  const float* bg = (const float*)d_in[6];
  float* out = (float*)d_out;
  uint8_t* wsb = (uint8_t*)d_ws;

  k_pre<<<768, 256, 0, stream>>>(x, W1, W2, wsb);
  k_gate<<<1, 256, 0, stream>>>(Wg, bg, b2, wsb);
  k_main<<<512, 768, 0, stream>>>(x, b1, wsb, out);
}